// Round 9
// baseline (11926.022 us; speedup 1.0000x reference)
//
#include <hip/hip_runtime.h>
#include <stddef.h>

typedef unsigned int u32;

#define TT 512
#define TC 64        // timestep chunk
#define NCHUNK 8

__device__ __forceinline__ float sigmoidf_(float x) {
    return 1.0f / (1.0f + __expf(-x));
}
__device__ __forceinline__ float tanhf_(float x) {
    float ax = fabsf(x);
    float e = __expf(-2.0f * ax);
    float t = (1.0f - e) / (1.0f + e);
    return copysignf(t, x);
}

// ---- per-access coherent (IF$-level) ops: no cache-wide inv/wb, no RMW ----
__device__ __forceinline__ float4 ldg_cv4(const float* p) {
    float4 v;
    asm volatile("global_load_dwordx4 %0, %1, off sc0 sc1\n\t"
                 "s_waitcnt vmcnt(0)"
                 : "=v"(v) : "v"(p) : "memory");
    return v;
}
__device__ __forceinline__ void stg_cv2(float* p, float2 v) {
    asm volatile("global_store_dwordx2 %0, %1, off sc0 sc1"
                 :: "v"(p), "v"(v) : "memory");
}

// ============================================================================
// proj2: paired input-projection GEMMs (z=0: set A, z=1: set B).
//   xW[tl][j][b] = sum_k W[j][k] * X[b*sXb + (tb + tl)*sXt + k] + bih[j] + bhh[j]
//   M=2048, N = 64t x 32b, K=512; tile 128x128, 256 threads, 8x8 register tile.
//   tb < 0 -> half inactive.
// ============================================================================
#define APITCH 132
#define BPITCH 132

__global__ void __launch_bounds__(256, 2)
proj2(const float* __restrict__ WA, const float* __restrict__ bihA,
      const float* __restrict__ bhhA, const float* __restrict__ XA,
      size_t sXbA, size_t sXtA, int tbA, float* __restrict__ xWA,
      const float* __restrict__ WB, const float* __restrict__ bihB,
      const float* __restrict__ bhhB, const float* __restrict__ XB,
      size_t sXbB, size_t sXtB, int tbB, float* __restrict__ xWB)
{
    const int half = blockIdx.z;
    const int tb = half ? tbB : tbA;
    if (tb < 0) return;
    const float* W   = half ? WB   : WA;
    const float* bih = half ? bihB : bihA;
    const float* bhh = half ? bhhB : bhhA;
    const float* X   = half ? XB   : XA;
    const size_t sXb = half ? sXbB : sXbA;
    const size_t sXt = half ? sXtB : sXtA;
    float* xW        = half ? xWB  : xWA;

    __shared__ float As[32][APITCH];   // [k][m]
    __shared__ float Bs[32][BPITCH];   // [k][n]
    const int tid = threadIdx.x;
    const int mbase = blockIdx.x * 128;
    const int nt = blockIdx.y;
    const int tm = tid >> 4;
    const int tn = tid & 15;
    float acc[8][8] = {};

    for (int kc = 0; kc < 512; kc += 32) {
        __syncthreads();
#pragma unroll
        for (int u = 0; u < 4; ++u) {
            const int f = u * 256 + tid;
            const int m = f >> 3, k4 = f & 7;
            const float4 v = *(const float4*)(W + (size_t)(mbase + m) * 512 + kc + k4 * 4);
            As[k4 * 4 + 0][m] = v.x; As[k4 * 4 + 1][m] = v.y;
            As[k4 * 4 + 2][m] = v.z; As[k4 * 4 + 3][m] = v.w;
        }
#pragma unroll
        for (int u = 0; u < 4; ++u) {
            const int f = u * 256 + tid;
            const int n = f >> 3, k4 = f & 7;
            const int tl = n >> 5, b = n & 31;
            const float4 v = *(const float4*)(X + (size_t)b * sXb +
                                              (size_t)(tb + nt * 4 + tl) * sXt + kc + k4 * 4);
            Bs[k4 * 4 + 0][n] = v.x; Bs[k4 * 4 + 1][n] = v.y;
            Bs[k4 * 4 + 2][n] = v.z; Bs[k4 * 4 + 3][n] = v.w;
        }
        __syncthreads();
#pragma unroll 8
        for (int kk = 0; kk < 32; ++kk) {
            const float4 a0 = *(const float4*)&As[kk][tm * 8];
            const float4 a1 = *(const float4*)&As[kk][tm * 8 + 4];
            const float4 b0 = *(const float4*)&Bs[kk][tn * 8];
            const float4 b1 = *(const float4*)&Bs[kk][tn * 8 + 4];
            const float am[8] = {a0.x,a0.y,a0.z,a0.w,a1.x,a1.y,a1.z,a1.w};
            const float bn[8] = {b0.x,b0.y,b0.z,b0.w,b1.x,b1.y,b1.z,b1.w};
#pragma unroll
            for (int i = 0; i < 8; ++i)
#pragma unroll
                for (int j = 0; j < 8; ++j)
                    acc[i][j] = fmaf(am[i], bn[j], acc[i][j]);
        }
    }
    const int tl_loc = nt * 4 + (tn >> 2);
    const int bcol = (tn & 3) * 8;
#pragma unroll
    for (int i = 0; i < 8; ++i) {
        const int m = mbase + tm * 8 + i;
        const float bias = bih[m] + bhh[m];
        float* dst = xW + ((size_t)tl_loc * 2048 + m) * 32 + bcol;
        float4 v0 = {acc[i][0] + bias, acc[i][1] + bias, acc[i][2] + bias, acc[i][3] + bias};
        float4 v1 = {acc[i][4] + bias, acc[i][5] + bias, acc[i][6] + bias, acc[i][7] + bias};
        *(float4*)dst = v0;
        *(float4*)(dst + 4) = v1;
    }
}

// ============================================================================
// lstm_rec2: paired recurrences (bid<256: set A, bid>=256: set B), independent.
//   Per half: 256 blocks x 512 threads, 2 blocks/CU when both halves active.
//   chain = lb&7 (4 batches), rbi = lb>>3 (16 hidden -> 64 gate rows).
//   Thread (rgrp=tid>>4 -> 2 rows, ks=tid&15 -> 32-wide k-slice): w[2][32] VGPRs.
//   Sync: tagged-data ring (h,tag) pairs, sc0sc1, depth 4. No atomics/fences.
//   Reduce: LDS transpose (part[256][20]) instead of shuffle butterfly.
//   t0 < 0 -> half inactive. hbuf addressed as hbuf + (t - tsub)*sT + b*sB + h.
// ============================================================================
__global__ void __launch_bounds__(512, 4)
lstm_rec2(const float* __restrict__ WhhA, const float* __restrict__ xWA,
          float* __restrict__ hbufA, size_t sTA, size_t sBA, int tsubA,
          float* __restrict__ cstA, float* __restrict__ ringA, int t0A,
          const float* __restrict__ WhhB, const float* __restrict__ xWB,
          float* __restrict__ hbufB, size_t sTB, size_t sBB, int tsubB,
          float* __restrict__ cstB, float* __restrict__ ringB, int t0B)
{
    const int half = blockIdx.x >> 8;
    const int t0 = half ? t0B : t0A;
    if (t0 < 0) return;
    const float* Whh = half ? WhhB : WhhA;
    const float* xW  = half ? xWB  : xWA;
    float* hbuf      = half ? hbufB : hbufA;
    const size_t sT  = half ? sTB : sTA;
    const size_t sB  = half ? sBB : sBA;
    const int tsub   = half ? tsubB : tsubA;
    float* cst       = half ? cstB : cstA;
    float* ring      = half ? ringB : ringA;

    __shared__ float xh[4][512];     //  8 KB quad-swizzled h(t-1)
    __shared__ float part[256][20];  // 20 KB partials (pitch 20 -> b128-clean)
    __shared__ float gl[16][4][4];   //  1 KB [hl][b][gate]

    const int tid = threadIdx.x;
    const int lb = blockIdx.x & 255;
    const int chain = lb & 7;
    const int rbi = lb >> 3;
    const int hb = rbi * 16;                 // hidden slice [hb, hb+16)
    const int bb = chain * 4;                // batch slice [bb, bb+4)

    const int rgrp = tid >> 4;               // 0..31 -> rows rgrp*2, rgrp*2+1
    const int ks = tid & 15;                 // 0..15 -> k in [ks*32, ks*32+32)
    const int ks7 = ks & 7;

    // ---- load W_hh slice into registers (once): 2 rows x 32 k = 64 VGPRs ----
    float w[2][32];
#pragma unroll
    for (int i = 0; i < 2; ++i) {
        const int r = rgrp * 2 + i;                       // gate g=r>>4, hl=r&15
        const int j = ((r >> 4) << 9) + hb + (r & 15);
#pragma unroll
        for (int q8 = 0; q8 < 8; ++q8) {
            const float4 v = *(const float4*)(Whh + (size_t)j * 512 + ks * 32 + q8 * 4);
            w[i][q8 * 4 + 0] = v.x; w[i][q8 * 4 + 1] = v.y;
            w[i][q8 * 4 + 2] = v.z; w[i][q8 * 4 + 3] = v.w;
        }
    }
    // reducer decode (tid<256): one output (row r_r, batch b_r); part row == tid
    const int r_r = tid >> 2, b_r = tid & 3;
    const int j_r = ((r_r >> 4) << 9) + hb + (r_r & 15);
    // staging decode: all 512 threads, 4 h-values each
    const int b_s = tid >> 7, q = tid & 127;
    const float* rq_base = ring + ((size_t)(bb + b_s) * 512 + (q << 2)) * 2;
    // update decode (tid<64)
    const int b_u = tid >> 4, hl_u = tid & 15;
    float c_reg = 0.0f;
    if (tid < 64) c_reg = cst[(size_t)(bb + b_u) * 512 + hb + hl_u];

    __syncthreads();

    for (int t = t0; t < t0 + TC; ++t) {
        // prefetch precomputed input-projection (plain cached load, no dependency)
        float xwv = 0.0f;
        if (tid < 256)
            xwv = xW[((size_t)(t - t0) * 2048 + j_r) * 32 + bb + b_r];

        if (t > 0) {
            // poll-stage h(t-1): tags arrive WITH the data (single round trip)
            const float* pA = rq_base + (size_t)((t - 1) & 3) * (32 * 512 * 2);
            const u32 tt = (u32)t;
            float4 A, Bv;
            do {
                A  = ldg_cv4(pA);
                Bv = ldg_cv4(pA + 4);
            } while (__float_as_uint(A.y) != tt || __float_as_uint(A.w) != tt ||
                     __float_as_uint(Bv.y) != tt || __float_as_uint(Bv.w) != tt);
            const float4 hq = {A.x, A.z, Bv.x, Bv.z};
            const int swq = q ^ ((q >> 3) & 7);          // bijective, conflict-free
            *(float4*)&xh[b_s][swq << 2] = hq;
        }
        __syncthreads();                                  // sync1: xh ready

        float acc[2][4] = {};
        if (t > 0) {
#pragma unroll
            for (int jj = 0; jj < 8; ++jj) {
                const int sq = ((ks << 3) + (jj ^ ks7)) << 2;   // swizzled quad
                const float4 x0 = *(const float4*)&xh[0][sq];
                const float4 x1 = *(const float4*)&xh[1][sq];
                const float4 x2 = *(const float4*)&xh[2][sq];
                const float4 x3 = *(const float4*)&xh[3][sq];
#pragma unroll
                for (int i = 0; i < 2; ++i) {
                    acc[i][0] = fmaf(w[i][jj*4+0], x0.x, acc[i][0]);
                    acc[i][0] = fmaf(w[i][jj*4+1], x0.y, acc[i][0]);
                    acc[i][0] = fmaf(w[i][jj*4+2], x0.z, acc[i][0]);
                    acc[i][0] = fmaf(w[i][jj*4+3], x0.w, acc[i][0]);
                    acc[i][1] = fmaf(w[i][jj*4+0], x1.x, acc[i][1]);
                    acc[i][1] = fmaf(w[i][jj*4+1], x1.y, acc[i][1]);
                    acc[i][1] = fmaf(w[i][jj*4+2], x1.z, acc[i][1]);
                    acc[i][1] = fmaf(w[i][jj*4+3], x1.w, acc[i][1]);
                    acc[i][2] = fmaf(w[i][jj*4+0], x2.x, acc[i][2]);
                    acc[i][2] = fmaf(w[i][jj*4+1], x2.y, acc[i][2]);
                    acc[i][2] = fmaf(w[i][jj*4+2], x2.z, acc[i][2]);
                    acc[i][2] = fmaf(w[i][jj*4+3], x2.w, acc[i][2]);
                    acc[i][3] = fmaf(w[i][jj*4+0], x3.x, acc[i][3]);
                    acc[i][3] = fmaf(w[i][jj*4+1], x3.y, acc[i][3]);
                    acc[i][3] = fmaf(w[i][jj*4+2], x3.z, acc[i][3]);
                    acc[i][3] = fmaf(w[i][jj*4+3], x3.w, acc[i][3]);
                }
            }
        }
        // partials -> LDS transpose (replaces shuffle butterfly)
#pragma unroll
        for (int i = 0; i < 2; ++i)
#pragma unroll
            for (int b = 0; b < 4; ++b)
                part[((rgrp * 2 + i) << 2) + b][ks] = acc[i][b];
        __syncthreads();                                  // sync2: partials ready
        if (tid < 256) {
            const float* row = part[tid];
            const float4 p0 = *(const float4*)(row + 0);
            const float4 p1 = *(const float4*)(row + 4);
            const float4 p2 = *(const float4*)(row + 8);
            const float4 p3 = *(const float4*)(row + 12);
            const float s0 = ((p0.x + p0.y) + (p0.z + p0.w)) +
                             ((p1.x + p1.y) + (p1.z + p1.w));
            const float s1 = ((p2.x + p2.y) + (p2.z + p2.w)) +
                             ((p3.x + p3.y) + (p3.z + p3.w));
            gl[r_r & 15][b_r][r_r >> 4] = (s0 + s1) + xwv;
        }
        __syncthreads();                                  // sync3: gates ready
        if (tid < 64) {  // one thread per (batch, hidden) pair
            const float4 gv = *(const float4*)&gl[hl_u][b_u][0];
            const float i_ = sigmoidf_(gv.x);
            const float f_ = sigmoidf_(gv.y);
            const float g_ = tanhf_(gv.z);
            const float o_ = sigmoidf_(gv.w);
            c_reg = f_ * c_reg + i_ * g_;
            const float hv = o_ * tanhf_(c_reg);
            // plain store for cross-dispatch consumers (GEMM / final output)
            hbuf[(size_t)(t - tsub) * sT + (size_t)(bb + b_u) * sB + hb + hl_u] = hv;
            // tagged publication: data and tag land together, no fence, no flag
            float2 pr; pr.x = hv; pr.y = __uint_as_float((u32)(t + 1));
            stg_cv2(ring + ((size_t)(t & 3) * (32 * 512) +
                            (size_t)(bb + b_u) * 512 + hb + hl_u) * 2, pr);
        }
        // no end sync needed: next part-write is after sync1', next gl-write
        // after sync2', next xh-write only overwrites data dead since sync2.
    }
    if (tid < 64) cst[(size_t)(bb + b_u) * 512 + hb + hl_u] = c_reg;
}

// ============================================================================
extern "C" void kernel_launch(void* const* d_in, const int* in_sizes, int n_in,
                              void* d_out, int out_size, void* d_ws, size_t ws_size,
                              hipStream_t stream) {
    const float* inp  = (const float*)d_in[0];
    const float* Wih0 = (const float*)d_in[1];
    const float* Whh0 = (const float*)d_in[2];
    const float* bih0 = (const float*)d_in[3];
    const float* bhh0 = (const float*)d_in[4];
    const float* Wih1 = (const float*)d_in[5];
    const float* Whh1 = (const float*)d_in[6];
    const float* bih1 = (const float*)d_in[7];
    const float* bhh1 = (const float*)d_in[8];
    float* out = (float*)d_out;

    char* ws = (char*)d_ws;
    const size_t CHf = (size_t)TC * 32 * 512;               // floats per h0 chunk slot
    float* h0ring = (float*)ws;                             // 2 x [64][32][512]  8 MB
    float* xW0    = (float*)(ws + 8388608);                 // [64][2048][32]    16 MB
    float* xW1    = (float*)(ws + 25165824);                // [64][2048][32]    16 MB
    float* cst0   = (float*)(ws + 41943040);                // [32][512]
    float* cst1   = cst0 + 32 * 512;
    float* ring0  = (float*)(ws + 42074112);                // [4][32][512]x2  512 KB
    float* ring1  = (float*)(ws + 42598400);                // [4][32][512]x2  512 KB
    (void)hipMemsetAsync(ws + 41943040, 0, 131072 + 2 * 524288, stream);

    const dim3 gg(16, 16, 2), gb(256);
    const dim3 rg(512), rb(512);
    const size_t sb_in = (size_t)512 * 512;                 // inp batch stride
    const size_t sT_h0 = (size_t)32 * 512;                  // h0 slot t stride

    // beat -1: g0(0) alone
    hipLaunchKernelGGL(proj2, gg, gb, 0, stream,
                       Wih0, bih0, bhh0, inp, sb_in, (size_t)512, 0, xW0,
                       Wih1, bih1, bhh1, inp, sb_in, (size_t)512, -1, xW1);
    // beat 0: r0(0) alone
    hipLaunchKernelGGL(lstm_rec2, rg, rb, 0, stream,
                       Whh0, xW0, h0ring, sT_h0, (size_t)512, 0, cst0, ring0, 0,
                       Whh1, xW1, out, (size_t)512, sb_in, 0, cst1, ring1, -1);

    for (int c = 0; c < NCHUNK; ++c) {
        const int t0A = (c + 1) * TC;
        const bool hasA = (c < NCHUNK - 1);
        const int t0B = c * TC;
        float* h0cur = h0ring + (size_t)(c & 1) * CHf;         // slot chunk c
        float* h0nxt = h0ring + (size_t)((c + 1) & 1) * CHf;   // slot chunk c+1
        // proj: A = g0(c+1) (x from inp, absolute t), B = g1(c) (x from h0 slot c)
        hipLaunchKernelGGL(proj2, gg, gb, 0, stream,
                           Wih0, bih0, bhh0, inp, sb_in, (size_t)512,
                           hasA ? t0A : -1, xW0,
                           Wih1, bih1, bhh1, h0cur, (size_t)512, sT_h0, 0, xW1);
        // rec: A = r0(c+1) -> h0 slot c+1 (t-local), B = r1(c) -> out (absolute t)
        hipLaunchKernelGGL(lstm_rec2, rg, rb, 0, stream,
                           Whh0, xW0, h0nxt, sT_h0, (size_t)512, t0A,
                           cst0, ring0, hasA ? t0A : -1,
                           Whh1, xW1, out, (size_t)512, sb_in, 0,
                           cst1, ring1, t0B);
    }
}

// Round 10
// 5124.036 us; speedup vs baseline: 2.3275x; 2.3275x over previous
//
#include <hip/hip_runtime.h>
#include <stddef.h>

typedef unsigned int u32;

#define TT 512
#define TC 64        // timestep chunk
#define NCHUNK 8

__device__ __forceinline__ float sigmoidf_(float x) {
    return 1.0f / (1.0f + __expf(-x));
}
__device__ __forceinline__ float tanhf_(float x) {
    float ax = fabsf(x);
    float e = __expf(-2.0f * ax);
    float t = (1.0f - e) / (1.0f + e);
    return copysignf(t, x);
}

// ---- per-access coherent (IF$-level) ops: no cache-wide inv/wb, no RMW ----
__device__ __forceinline__ float4 ldg_cv4(const float* p) {
    float4 v;
    asm volatile("global_load_dwordx4 %0, %1, off sc0 sc1\n\t"
                 "s_waitcnt vmcnt(0)"
                 : "=v"(v) : "v"(p) : "memory");
    return v;
}
__device__ __forceinline__ void stg_cv2(float* p, float2 v) {
    asm volatile("global_store_dwordx2 %0, %1, off sc0 sc1"
                 :: "v"(p), "v"(v) : "memory");
}

// ============================================================================
// proj2: paired input-projection GEMMs (z=0: set A, z=1: set B).
//   xW[tl][j][b] = sum_k W[j][k] * X[b*sXb + (tb + tl)*sXt + k] + bih[j] + bhh[j]
//   M=2048, N = 64t x 32b, K=512; tile 128x128, 256 threads, 8x8 register tile.
//   tb < 0 -> half inactive.
// ============================================================================
#define APITCH 132
#define BPITCH 132

__global__ void __launch_bounds__(256, 2)
proj2(const float* __restrict__ WA, const float* __restrict__ bihA,
      const float* __restrict__ bhhA, const float* __restrict__ XA,
      size_t sXbA, size_t sXtA, int tbA, float* __restrict__ xWA,
      const float* __restrict__ WB, const float* __restrict__ bihB,
      const float* __restrict__ bhhB, const float* __restrict__ XB,
      size_t sXbB, size_t sXtB, int tbB, float* __restrict__ xWB)
{
    const int half = blockIdx.z;
    const int tb = half ? tbB : tbA;
    if (tb < 0) return;
    const float* W   = half ? WB   : WA;
    const float* bih = half ? bihB : bihA;
    const float* bhh = half ? bhhB : bhhA;
    const float* X   = half ? XB   : XA;
    const size_t sXb = half ? sXbB : sXbA;
    const size_t sXt = half ? sXtB : sXtA;
    float* xW        = half ? xWB  : xWA;

    __shared__ float As[32][APITCH];   // [k][m]
    __shared__ float Bs[32][BPITCH];   // [k][n]
    const int tid = threadIdx.x;
    const int mbase = blockIdx.x * 128;
    const int nt = blockIdx.y;
    const int tm = tid >> 4;
    const int tn = tid & 15;
    float acc[8][8] = {};

    for (int kc = 0; kc < 512; kc += 32) {
        __syncthreads();
#pragma unroll
        for (int u = 0; u < 4; ++u) {
            const int f = u * 256 + tid;
            const int m = f >> 3, k4 = f & 7;
            const float4 v = *(const float4*)(W + (size_t)(mbase + m) * 512 + kc + k4 * 4);
            As[k4 * 4 + 0][m] = v.x; As[k4 * 4 + 1][m] = v.y;
            As[k4 * 4 + 2][m] = v.z; As[k4 * 4 + 3][m] = v.w;
        }
#pragma unroll
        for (int u = 0; u < 4; ++u) {
            const int f = u * 256 + tid;
            const int n = f >> 3, k4 = f & 7;
            const int tl = n >> 5, b = n & 31;
            const float4 v = *(const float4*)(X + (size_t)b * sXb +
                                              (size_t)(tb + nt * 4 + tl) * sXt + kc + k4 * 4);
            Bs[k4 * 4 + 0][n] = v.x; Bs[k4 * 4 + 1][n] = v.y;
            Bs[k4 * 4 + 2][n] = v.z; Bs[k4 * 4 + 3][n] = v.w;
        }
        __syncthreads();
#pragma unroll 8
        for (int kk = 0; kk < 32; ++kk) {
            const float4 a0 = *(const float4*)&As[kk][tm * 8];
            const float4 a1 = *(const float4*)&As[kk][tm * 8 + 4];
            const float4 b0 = *(const float4*)&Bs[kk][tn * 8];
            const float4 b1 = *(const float4*)&Bs[kk][tn * 8 + 4];
            const float am[8] = {a0.x,a0.y,a0.z,a0.w,a1.x,a1.y,a1.z,a1.w};
            const float bn[8] = {b0.x,b0.y,b0.z,b0.w,b1.x,b1.y,b1.z,b1.w};
#pragma unroll
            for (int i = 0; i < 8; ++i)
#pragma unroll
                for (int j = 0; j < 8; ++j)
                    acc[i][j] = fmaf(am[i], bn[j], acc[i][j]);
        }
    }
    const int tl_loc = nt * 4 + (tn >> 2);
    const int bcol = (tn & 3) * 8;
#pragma unroll
    for (int i = 0; i < 8; ++i) {
        const int m = mbase + tm * 8 + i;
        const float bias = bih[m] + bhh[m];
        float* dst = xW + ((size_t)tl_loc * 2048 + m) * 32 + bcol;
        float4 v0 = {acc[i][0] + bias, acc[i][1] + bias, acc[i][2] + bias, acc[i][3] + bias};
        float4 v1 = {acc[i][4] + bias, acc[i][5] + bias, acc[i][6] + bias, acc[i][7] + bias};
        *(float4*)dst = v0;
        *(float4*)(dst + 4) = v1;
    }
}

// ============================================================================
// lstm_rec2: paired recurrences (bid<256: set A, bid>=256: set B), independent.
//   Body is EXACTLY R8's proven lstm_rec (112 VGPR, no spill, butterfly reduce).
//   launch_bounds(512, 1): natural ~112 VGPR -> 4 waves/SIMD -> 2 blocks/CU ->
//   both halves co-resident; if codegen exceeds 128, halves serialize (safe).
//   chain = lb&7 (4 batches), rbi = lb>>3 (16 hidden -> 64 gate rows).
//   Sync: tagged-data ring (h,tag) float2, sc0sc1, depth 4. No atomics/fences.
//   t0 < 0 -> half inactive. hbuf addressed as hbuf + (t - tsub)*sT + b*sB + h.
// ============================================================================
__global__ void __launch_bounds__(512, 1)
lstm_rec2(const float* __restrict__ WhhA, const float* __restrict__ xWA,
          float* __restrict__ hbufA, size_t sTA, size_t sBA, int tsubA,
          float* __restrict__ cstA, float* __restrict__ ringA, int t0A,
          const float* __restrict__ WhhB, const float* __restrict__ xWB,
          float* __restrict__ hbufB, size_t sTB, size_t sBB, int tsubB,
          float* __restrict__ cstB, float* __restrict__ ringB, int t0B)
{
    const int half = blockIdx.x >> 8;
    const int t0 = half ? t0B : t0A;
    if (t0 < 0) return;
    const float* Whh = half ? WhhB : WhhA;
    const float* xW  = half ? xWB  : xWA;
    float* hbuf      = half ? hbufB : hbufA;
    const size_t sT  = half ? sTB : sTA;
    const size_t sB  = half ? sBB : sBA;
    const int tsub   = half ? tsubB : tsubA;
    float* cst       = half ? cstB : cstA;
    float* ring      = half ? ringB : ringA;

    __shared__ float xh[4][512];             // quad-swizzled h(t-1)   8 KB
    __shared__ float gl[16][4][4];           // [hl][b][gate]          1 KB

    const int tid = threadIdx.x;
    const int lb = blockIdx.x & 255;
    const int chain = lb & 7;
    const int rbi = lb >> 3;
    const int hb = rbi * 16;                 // hidden slice [hb, hb+16)
    const int bb = chain * 4;                // batch slice [bb, bb+4)

    const int rgrp = tid >> 4;               // 0..31 -> rows rgrp*2, rgrp*2+1
    const int ks = tid & 15;                 // 0..15 -> k in [ks*32, ks*32+32)
    const int ks7 = ks & 7;

    // ---- load W_hh slice into registers (once): 2 rows x 32 k = 64 VGPRs ----
    float w[2][32];
#pragma unroll
    for (int i = 0; i < 2; ++i) {
        const int r = rgrp * 2 + i;                       // gate g=r>>4, hl=r&15
        const int j = ((r >> 4) << 9) + hb + (r & 15);
#pragma unroll
        for (int q8 = 0; q8 < 8; ++q8) {
            const float4 v = *(const float4*)(Whh + (size_t)j * 512 + ks * 32 + q8 * 4);
            w[i][q8 * 4 + 0] = v.x; w[i][q8 * 4 + 1] = v.y;
            w[i][q8 * 4 + 2] = v.z; w[i][q8 * 4 + 3] = v.w;
        }
    }
    // xwv-lane decode (ks<8): lane adds xW for (row i_x = ks>>2, batch b_x = ks&3)
    const int i_x = ks >> 2, b_x = ks & 3;
    const int r_x = rgrp * 2 + i_x;
    const int j_x = ((r_x >> 4) << 9) + hb + (r_x & 15);
    // consumer staging decode: batch b_s, h-quad q
    const int b_s = tid >> 7, q = tid & 127;
    const float* rq_base = ring + ((size_t)(bb + b_s) * 512 + (q << 2)) * 2;
    // update decode (tid<64)
    const int b_u = tid >> 4, hl_u = tid & 15;
    float c_reg = 0.0f;
    if (tid < 64) c_reg = cst[(size_t)(bb + b_u) * 512 + hb + hl_u];

    __syncthreads();

    for (int t = t0; t < t0 + TC; ++t) {
        // prefetch precomputed input-projection (plain cached load, no dependency)
        float xwv = 0.0f;
        if (ks < 8)
            xwv = xW[((size_t)(t - t0) * 2048 + j_x) * 32 + bb + b_x];

        if (t > 0) {
            // poll-stage h(t-1): tags arrive WITH the data (single round trip)
            const float* pA = rq_base + (size_t)((t - 1) & 3) * (32 * 512 * 2);
            const u32 tt = (u32)t;
            float4 A, Bv;
            do {
                A  = ldg_cv4(pA);
                Bv = ldg_cv4(pA + 4);
            } while (__float_as_uint(A.y) != tt || __float_as_uint(A.w) != tt ||
                     __float_as_uint(Bv.y) != tt || __float_as_uint(Bv.w) != tt);
            const float4 hq = {A.x, A.z, Bv.x, Bv.z};
            const int swq = q ^ ((q >> 3) & 7);          // bijective, conflict-free
            *(float4*)&xh[b_s][swq << 2] = hq;
        }
        __syncthreads();

        float acc[2][4] = {};
        if (t > 0) {
#pragma unroll
            for (int jj = 0; jj < 8; ++jj) {
                const int sq = ((ks << 3) + (jj ^ ks7)) << 2;   // swizzled quad offset
                const float4 x0 = *(const float4*)&xh[0][sq];
                const float4 x1 = *(const float4*)&xh[1][sq];
                const float4 x2 = *(const float4*)&xh[2][sq];
                const float4 x3 = *(const float4*)&xh[3][sq];
#pragma unroll
                for (int i = 0; i < 2; ++i) {
                    acc[i][0] = fmaf(w[i][jj*4+0], x0.x, acc[i][0]);
                    acc[i][0] = fmaf(w[i][jj*4+1], x0.y, acc[i][0]);
                    acc[i][0] = fmaf(w[i][jj*4+2], x0.z, acc[i][0]);
                    acc[i][0] = fmaf(w[i][jj*4+3], x0.w, acc[i][0]);
                    acc[i][1] = fmaf(w[i][jj*4+0], x1.x, acc[i][1]);
                    acc[i][1] = fmaf(w[i][jj*4+1], x1.y, acc[i][1]);
                    acc[i][1] = fmaf(w[i][jj*4+2], x1.z, acc[i][1]);
                    acc[i][1] = fmaf(w[i][jj*4+3], x1.w, acc[i][1]);
                    acc[i][2] = fmaf(w[i][jj*4+0], x2.x, acc[i][2]);
                    acc[i][2] = fmaf(w[i][jj*4+1], x2.y, acc[i][2]);
                    acc[i][2] = fmaf(w[i][jj*4+2], x2.z, acc[i][2]);
                    acc[i][2] = fmaf(w[i][jj*4+3], x2.w, acc[i][2]);
                    acc[i][3] = fmaf(w[i][jj*4+0], x3.x, acc[i][3]);
                    acc[i][3] = fmaf(w[i][jj*4+1], x3.y, acc[i][3]);
                    acc[i][3] = fmaf(w[i][jj*4+2], x3.z, acc[i][3]);
                    acc[i][3] = fmaf(w[i][jj*4+3], x3.w, acc[i][3]);
                }
            }
        }
        // fold xW in (each of the 8 outputs added by exactly one of lanes ks<8)
        if (ks < 8) acc[i_x][b_x] += xwv;
        // butterfly reduce over the 16 k-slice lanes (4 stages x 8 accs)
#pragma unroll
        for (int m = 1; m < 16; m <<= 1) {
#pragma unroll
            for (int i = 0; i < 2; ++i) {
#pragma unroll
                for (int b = 0; b < 4; ++b)
                    acc[i][b] += __shfl_xor(acc[i][b], m);
            }
        }
        if (ks == 0) {
#pragma unroll
            for (int i = 0; i < 2; ++i) {
                const int r = rgrp * 2 + i;
#pragma unroll
                for (int b = 0; b < 4; ++b)
                    gl[r & 15][b][r >> 4] = acc[i][b];
            }
        }
        __syncthreads();
        if (tid < 64) {  // one thread per (batch, hidden) pair
            const float4 gv = *(const float4*)&gl[hl_u][b_u][0];
            const float i_ = sigmoidf_(gv.x);
            const float f_ = sigmoidf_(gv.y);
            const float g_ = tanhf_(gv.z);
            const float o_ = sigmoidf_(gv.w);
            c_reg = f_ * c_reg + i_ * g_;
            const float hv = o_ * tanhf_(c_reg);
            // plain store for cross-dispatch consumers (GEMM / final output)
            hbuf[(size_t)(t - tsub) * sT + (size_t)(bb + b_u) * sB + hb + hl_u] = hv;
            // tagged publication: data and tag land together, no fence, no flag
            float2 pr; pr.x = hv; pr.y = __uint_as_float((u32)(t + 1));
            stg_cv2(ring + ((size_t)(t & 3) * (32 * 512) +
                            (size_t)(bb + b_u) * 512 + hb + hl_u) * 2, pr);
        }
        __syncthreads();
    }
    if (tid < 64) cst[(size_t)(bb + b_u) * 512 + hb + hl_u] = c_reg;
}

// ============================================================================
extern "C" void kernel_launch(void* const* d_in, const int* in_sizes, int n_in,
                              void* d_out, int out_size, void* d_ws, size_t ws_size,
                              hipStream_t stream) {
    const float* inp  = (const float*)d_in[0];
    const float* Wih0 = (const float*)d_in[1];
    const float* Whh0 = (const float*)d_in[2];
    const float* bih0 = (const float*)d_in[3];
    const float* bhh0 = (const float*)d_in[4];
    const float* Wih1 = (const float*)d_in[5];
    const float* Whh1 = (const float*)d_in[6];
    const float* bih1 = (const float*)d_in[7];
    const float* bhh1 = (const float*)d_in[8];
    float* out = (float*)d_out;

    char* ws = (char*)d_ws;
    const size_t CHf = (size_t)TC * 32 * 512;               // floats per h0 chunk slot
    float* h0ring = (float*)ws;                             // 2 x [64][32][512]  8 MB
    float* xW0    = (float*)(ws + 8388608);                 // [64][2048][32]    16 MB
    float* xW1    = (float*)(ws + 25165824);                // [64][2048][32]    16 MB
    float* cst0   = (float*)(ws + 41943040);                // [32][512]
    float* cst1   = cst0 + 32 * 512;
    float* ring0  = (float*)(ws + 42074112);                // [4][32][512]x2  512 KB
    float* ring1  = (float*)(ws + 42598400);                // [4][32][512]x2  512 KB
    (void)hipMemsetAsync(ws + 41943040, 0, 131072 + 2 * 524288, stream);

    const dim3 gg(16, 16, 2), gb(256);
    const dim3 rg(512), rb(512);
    const size_t sb_in = (size_t)512 * 512;                 // inp batch stride
    const size_t sT_h0 = (size_t)32 * 512;                  // h0 slot t stride

    // beat -1: g0(0) alone
    hipLaunchKernelGGL(proj2, gg, gb, 0, stream,
                       Wih0, bih0, bhh0, inp, sb_in, (size_t)512, 0, xW0,
                       Wih1, bih1, bhh1, inp, sb_in, (size_t)512, -1, xW1);
    // beat 0: r0(0) alone
    hipLaunchKernelGGL(lstm_rec2, rg, rb, 0, stream,
                       Whh0, xW0, h0ring, sT_h0, (size_t)512, 0, cst0, ring0, 0,
                       Whh1, xW1, out, (size_t)512, sb_in, 0, cst1, ring1, -1);

    for (int c = 0; c < NCHUNK; ++c) {
        const int t0A = (c + 1) * TC;
        const bool hasA = (c < NCHUNK - 1);
        const int t0B = c * TC;
        float* h0cur = h0ring + (size_t)(c & 1) * CHf;         // slot chunk c
        float* h0nxt = h0ring + (size_t)((c + 1) & 1) * CHf;   // slot chunk c+1
        // proj: A = g0(c+1) (x from inp, absolute t), B = g1(c) (x from h0 slot c)
        hipLaunchKernelGGL(proj2, gg, gb, 0, stream,
                           Wih0, bih0, bhh0, inp, sb_in, (size_t)512,
                           hasA ? t0A : -1, xW0,
                           Wih1, bih1, bhh1, h0cur, (size_t)512, sT_h0, 0, xW1);
        // rec: A = r0(c+1) -> h0 slot c+1 (t-local), B = r1(c) -> out (absolute t)
        hipLaunchKernelGGL(lstm_rec2, rg, rb, 0, stream,
                           Whh0, xW0, h0nxt, sT_h0, (size_t)512, t0A,
                           cst0, ring0, hasA ? t0A : -1,
                           Whh1, xW1, out, (size_t)512, sb_in, 0,
                           cst1, ring1, t0B);
    }
}